// Round 2
// baseline (720.134 us; speedup 1.0000x reference)
//
#include <hip/hip_runtime.h>
#include <stdint.h>
#include <math.h>

#define TPB 256
#define CAP 2048      // stage-1 candidate capacity (power of two)
#define KTOP 100

// ---- f32 softmax positive channel, bit-emulating a numpy float32 mirror ----
// np mirror: m = max(x0,x1); e_i = exp_f32(x_i - m); p1 = e1 / (e0 + e1).
// exp_f32 emulated as correctly-rounded via double; exp(0) == 1.0 exactly.
// All f32 steps forced to IEEE round-to-nearest (no contraction).
__device__ __forceinline__ float np_softmax_p1(float x0, float x1) {
    float m = fmaxf(x0, x1);
    float a = __fsub_rn(x0, m);          // one of a,b is exactly 0
    float b = __fsub_rn(x1, m);
    float t = fminf(a, b);               // the (possibly) nonzero exponent arg
    float et = (float)exp((double)t);    // correctly-rounded f32 exp
    float e0 = (a == 0.0f) ? 1.0f : et;
    float e1 = (b == 0.0f) ? 1.0f : et;
    return __fdiv_rn(e1, __fadd_rn(e0, e1));
}

// Sort key: (p_bits << 32) | ~idx. p > 0 for all real cells, so p's f32 bit
// pattern is order-preserving as u32. Larger key = higher p, then lower idx
// (jax.lax.top_k tie convention). Padding key 0 decodes to invalid idx.
__device__ __forceinline__ uint64_t make_key(float p, int idx) {
    return ((uint64_t)__float_as_uint(p) << 32) | (uint32_t)(~idx);
}
__device__ __forceinline__ int key_idx(uint64_t k) { return (int)(~(uint32_t)k); }
__device__ __forceinline__ float key_p(uint64_t k) { return __uint_as_float((uint32_t)(k >> 32)); }

// In-LDS bitonic sort on u64 keys, descending (best at index 0). N = pow2.
__device__ void bitonic_sort(uint64_t* keys, int N) {
    for (int k = 2; k <= N; k <<= 1) {
        for (int j = k >> 1; j > 0; j >>= 1) {
            for (int i = threadIdx.x; i < N; i += TPB) {
                int ixj = i ^ j;
                if (ixj > i) {
                    uint64_t ka = keys[i], kb = keys[ixj];
                    bool sw = ((ka < kb) == ((i & k) == 0));
                    if (sw) { keys[i] = kb; keys[ixj] = ka; }
                }
            }
            __syncthreads();
        }
    }
}

// ---- stage 1: per-slice NMS + top-100 candidate indices --------------------
// x: [B,2,h,w] f32. Block = rows [s*sliceRows, +sliceRows) of image b, with
// +/-1 halo row. Out-of-image p = -1 (mirrors reduce_window -inf padding).
__global__ void stage1(const float* __restrict__ x, int h, int w,
                       int sliceRows, int nSlices, int* __restrict__ idx_out)
{
    const int s = blockIdx.x;
    const int b = blockIdx.y;
    const int r0 = s * sliceRows;
    const int r1 = min(r0 + sliceRows, h);
    const int tileRows = sliceRows + 2;

    extern __shared__ unsigned char smem[];
    float*    pf   = (float*)smem;                              // tileRows * w
    uint64_t* keys = (uint64_t*)(smem + (size_t)tileRows * w * 4);
    __shared__ int cnt;
    if (threadIdx.x == 0) cnt = 0;

    const float* x0 = x + (size_t)b * 2 * h * w;
    const float* x1 = x0 + (size_t)h * w;

    // Load p tile for rows r0-1 .. r0+sliceRows
    for (int t = threadIdx.x; t < tileRows * w; t += TPB) {
        int tr = t / w, c = t - tr * w;
        int r = r0 - 1 + tr;
        float v = -1.0f;
        if (r >= 0 && r < h) {
            int off = r * w + c;
            v = np_softmax_p1(x0[off], x1[off]);
        }
        pf[t] = v;
    }
    __syncthreads();

    // 3x3 NMS in f32 p-space: keep iff p >= all 8 neighbors (ties keep both,
    // matching reference's x == window_max).
    const int cells = (r1 - r0) * w;
    for (int t = threadIdx.x; t < cells; t += TPB) {
        int lr = t / w, c = t - lr * w;
        int tr = lr + 1;
        float v = pf[tr * w + c];
        bool keep = true;
        int c0 = max(c - 1, 0), c1 = min(c + 1, w - 1);
        for (int rr = tr - 1; rr <= tr + 1 && keep; ++rr) {
            for (int cc = c0; cc <= c1; ++cc) {
                if (rr == tr && cc == c) continue;
                if (pf[rr * w + cc] > v) { keep = false; break; }
            }
        }
        if (keep) {
            int pos = atomicAdd(&cnt, 1);
            if (pos < CAP) keys[pos] = make_key(v, (r0 + lr) * w + c);
        }
    }
    __syncthreads();

    int n = min(cnt, CAP);
    for (int t = n + threadIdx.x; t < CAP; t += TPB) keys[t] = 0;
    __syncthreads();
    bitonic_sort(keys, CAP);
    int* dst = idx_out + (size_t)(b * nSlices + s) * KTOP;
    for (int j = threadIdx.x; j < KTOP; j += TPB) dst[j] = key_idx(keys[j]);
}

// ---- stage 2: merge slice candidates, global top-100, decode boxes ---------
__global__ void stage2(const float* __restrict__ x, const float* __restrict__ bbox,
                       int h, int w, int nSlices, float ds, float fixedSize,
                       const int* __restrict__ idx_in, float* __restrict__ out)
{
    const int b = blockIdx.x;
    const int M = nSlices * KTOP;
    int N = 1; while (N < M) N <<= 1;     // 512 (player) / 2048 (ball)

    extern __shared__ unsigned char smem[];
    uint64_t* keys = (uint64_t*)smem;

    const float* x0 = x + (size_t)b * 2 * h * w;
    const float* x1 = x0 + (size_t)h * w;

    for (int t = threadIdx.x; t < N; t += TPB) {
        uint64_t u = 0;
        if (t < M) {
            int cand = idx_in[(size_t)b * M + t];
            if (cand >= 0 && cand < h * w)
                u = make_key(np_softmax_p1(x0[cand], x1[cand]), cand);
        }
        keys[t] = u;
    }
    __syncthreads();
    bitonic_sort(keys, N);

    for (int j = threadIdx.x; j < KTOP; j += TPB) {
        uint64_t k = keys[j];
        int id = key_idx(k);
        float o0 = 0.f, o1 = 0.f, o2 = 0.f, o3 = 0.f, val = 0.f;
        if (id >= 0 && id < h * w) {
            val = key_p(k);
            int yy = id / w, xx = id - yy * w;
            float xc = (float)xx * ds + (ds - 1.0f) * 0.5f;
            float yc = (float)yy * ds + (ds - 1.0f) * 0.5f;
            float t0 = 0.f, t1 = 0.f, t2 = fixedSize, t3 = fixedSize;
            if (bbox) {
                size_t base = (size_t)b * 4 * h * w + id;
                float sx = (float)w * ds, sy = (float)h * ds;
                t0 = bbox[base]                     * sx;
                t1 = bbox[base + (size_t)h * w]     * sy;
                t2 = bbox[base + (size_t)2 * h * w] * sx;
                t3 = bbox[base + (size_t)3 * h * w] * sy;
            }
            float bx = xc + t0, by = yc + t1;
            o0 = bx - 0.5f * t2;
            o1 = by - 0.5f * t3;
            o2 = bx + 0.5f * t2;
            o3 = by + 0.5f * t3;
        }
        float* op = out + ((size_t)b * KTOP + j) * 5;
        op[0] = o0; op[1] = o1; op[2] = o2; op[3] = o3; op[4] = val;
    }
}

// ---- launch -----------------------------------------------------------------
extern "C" void kernel_launch(void* const* d_in, const int* in_sizes, int n_in,
                              void* d_out, int out_size, void* d_ws, size_t ws_size,
                              hipStream_t stream) {
    const float* pmap  = (const float*)d_in[0];   // [64,2,68,120]
    const float* pbbox = (const float*)d_in[1];   // [64,4,68,120]
    const float* bmap  = (const float*)d_in[2];   // [64,2,272,480]
    float* out = (float*)d_out;                   // player [64,100,5] then ball [64,100,5]

    const int B = 64;
    const int HP = 68, WP = 120, HB = 272, WB = 480;
    const int P_SLICES = 4, B_SLICES = 16, SLICE_ROWS = 17;

    int* ws_pidx = (int*)d_ws;                          // 64*4*100 ints
    int* ws_bidx = ws_pidx + B * P_SLICES * KTOP;       // 64*16*100 ints

    size_t lds_p1 = (size_t)(SLICE_ROWS + 2) * WP * 4 + (size_t)CAP * 8;
    stage1<<<dim3(P_SLICES, B), TPB, lds_p1, stream>>>(pmap, HP, WP, SLICE_ROWS, P_SLICES, ws_pidx);

    size_t lds_b1 = (size_t)(SLICE_ROWS + 2) * WB * 4 + (size_t)CAP * 8;
    stage1<<<dim3(B_SLICES, B), TPB, lds_b1, stream>>>(bmap, HB, WB, SLICE_ROWS, B_SLICES, ws_bidx);

    stage2<<<B, TPB, (size_t)512 * 8, stream>>>(pmap, pbbox, HP, WP, P_SLICES,
                                                16.0f, 0.0f, ws_pidx, out);
    stage2<<<B, TPB, (size_t)2048 * 8, stream>>>(bmap, nullptr, HB, WB, B_SLICES,
                                                 4.0f, 40.0f, ws_bidx, out + (size_t)B * KTOP * 5);
}

// Round 3
// 642.897 us; speedup vs baseline: 1.1201x; 1.1201x over previous
//
#include <hip/hip_runtime.h>
#include <stdint.h>
#include <math.h>

#define TPB 256
#define KTOP 100
#define KSLICE 128   // per-slice candidates emitted (margin over KTOP for p-ties)

// ============================================================================
// np-f32 softmax positive channel is a MONOTONE function G of D = fl32(x1-x0):
//   t = -|D|; et = f32(exp_f64(t));  D>0: p=1/(et+1)  else: p=et/(1+et)
// (bit-identical to the validated round-2 emulation of the numpy mirror).
// Ordering by D == ordering by p, except G may collapse distinct D to equal p;
// collapse requires |dD| < ~6e-8 * e^|D| (< 0.25 for |D| < 15).
// ============================================================================
__device__ __forceinline__ float G_exact(float D) {
    float t = -fabsf(D);
    float etf = (float)exp((double)t);       // correctly-rounded f32 exp
    return (D > 0.0f) ? __fdiv_rn(1.0f, __fadd_rn(etf, 1.0f))
                      : __fdiv_rn(etf, __fadd_rn(1.0f, etf));
}

// Order-preserving f32 -> u32 (handles negatives), and its inverse.
__device__ __forceinline__ uint32_t flip_f32(float D) {
    uint32_t u = __float_as_uint(D);
    return (u & 0x80000000u) ? ~u : (u | 0x80000000u);
}
__device__ __forceinline__ float unflip_f32(uint32_t k) {
    uint32_t u = (k & 0x80000000u) ? (k ^ 0x80000000u) : ~k;
    return __uint_as_float(u);
}

// key = (orderbits << 32) | ~idx : descending sort => value desc, idx asc.
__device__ __forceinline__ uint64_t make_key(uint32_t orderbits, int idx) {
    return ((uint64_t)orderbits << 32) | (uint32_t)(~idx);
}
__device__ __forceinline__ int key_idx(uint64_t k) { return (int)(~(uint32_t)k); }

// In-LDS bitonic sort on u64 keys, descending. N = power of two.
__device__ void bitonic_sort(uint64_t* keys, int N) {
    for (int k = 2; k <= N; k <<= 1) {
        for (int j = k >> 1; j > 0; j >>= 1) {
            for (int i = threadIdx.x; i < N; i += TPB) {
                int ixj = i ^ j;
                if (ixj > i) {
                    uint64_t ka = keys[i], kb = keys[ixj];
                    bool sw = ((ka < kb) == ((i & k) == 0));
                    if (sw) { keys[i] = kb; keys[ixj] = ka; }
                }
            }
            __syncthreads();
        }
    }
}

// ---- stage 1: D-space NMS + per-slice top-KSLICE keys ----------------------
// x: [B,2,h,w]. Block = rows [s*sliceRows, +sliceRows) of image b, +/-1 halo
// row (-inf outside, mirroring reduce_window SAME padding in p-space).
__global__ void stage1(const float* __restrict__ x, int h, int w,
                       int sliceRows, int nSlices, int cap,
                       uint64_t* __restrict__ key_out)
{
    const int s = blockIdx.x;
    const int b = blockIdx.y;
    const int r0 = s * sliceRows;
    const int r1 = min(r0 + sliceRows, h);
    const int tileRows = sliceRows + 2;

    extern __shared__ unsigned char smem[];
    float*    df   = (float*)smem;                               // tileRows*w
    uint64_t* keys = (uint64_t*)(smem + (size_t)tileRows * w * 4);
    __shared__ int cnt;
    if (threadIdx.x == 0) cnt = 0;

    const float* x0 = x + (size_t)b * 2 * h * w;
    const float* x1 = x0 + (size_t)h * w;

    // Load D = fl(x1-x0) tile (no exp!)
    for (int t = threadIdx.x; t < tileRows * w; t += TPB) {
        int tr = t / w, c = t - tr * w;
        int r = r0 - 1 + tr;
        float v = -INFINITY;
        if (r >= 0 && r < h) {
            int off = r * w + c;
            v = __fsub_rn(x1[off], x0[off]);
        }
        df[t] = v;
    }
    __syncthreads();

    // NMS: ref keeps iff G(D) >= G(max neighbor D). Fast path in D-space;
    // exact double-exp compare only when D within the G-collapse window.
    const int cells = (r1 - r0) * w;
    for (int t = threadIdx.x; t < cells; t += TPB) {
        int lr = t / w, c = t - lr * w;
        int tr = lr + 1;
        float v = df[tr * w + c];
        int c0 = max(c - 1, 0), c1 = min(c + 1, w - 1);
        float mx = -INFINITY;
        for (int rr = tr - 1; rr <= tr + 1; ++rr)
            for (int cc = c0; cc <= c1; ++cc) {
                if (rr == tr && cc == c) continue;
                mx = fmaxf(mx, df[rr * w + cc]);
            }
        bool keep;
        if (v >= mx) keep = true;                                  // exact
        else if (mx - v >= 0.25f && mx < 13.0f) keep = false;      // G provably distinct
        else keep = (G_exact(v) == G_exact(mx));                   // rare tie check
        if (keep) {
            int pos = atomicAdd(&cnt, 1);
            if (pos < cap) keys[pos] = make_key(flip_f32(v), (r0 + lr) * w + c);
        }
    }
    __syncthreads();

    int n = min(cnt, cap);
    for (int t = n + threadIdx.x; t < cap; t += TPB) keys[t] = 0;
    __syncthreads();
    bitonic_sort(keys, cap);

    uint64_t* dst = key_out + (size_t)(b * nSlices + s) * KSLICE;
    for (int j = threadIdx.x; j < KSLICE; j += TPB) dst[j] = keys[j];
}

// ---- stage 2: exact-p re-rank of slice candidates + box decode -------------
// M = nSlices*KSLICE (power of two). Does not read the feature map: D comes
// from the stage-1 key; p = G_exact(D) matches the np softmax bit-for-bit.
__global__ void stage2(const float* __restrict__ bbox,
                       int h, int w, int M, float ds, float fixedSize,
                       const uint64_t* __restrict__ key_in, float* __restrict__ out)
{
    const int b = blockIdx.x;
    extern __shared__ unsigned char smem[];
    uint64_t* keys = (uint64_t*)smem;

    for (int t = threadIdx.x; t < M; t += TPB) {
        uint64_t kin = key_in[(size_t)b * M + t];
        int id = key_idx(kin);
        uint64_t u = 0;
        if ((unsigned)id < (unsigned)(h * w)) {
            float D = unflip_f32((uint32_t)(kin >> 32));
            float p = G_exact(D);
            u = make_key(__float_as_uint(p), id);   // p >= 0: bits order-preserving
        }
        keys[t] = u;
    }
    __syncthreads();
    bitonic_sort(keys, M);

    for (int j = threadIdx.x; j < KTOP; j += TPB) {
        uint64_t k = keys[j];
        int id = key_idx(k);
        float o0 = 0.f, o1 = 0.f, o2 = 0.f, o3 = 0.f, val = 0.f;
        if ((unsigned)id < (unsigned)(h * w)) {
            val = __uint_as_float((uint32_t)(k >> 32));
            int yy = id / w, xx = id - yy * w;
            float xc = (float)xx * ds + (ds - 1.0f) * 0.5f;
            float yc = (float)yy * ds + (ds - 1.0f) * 0.5f;
            float t0 = 0.f, t1 = 0.f, t2 = fixedSize, t3 = fixedSize;
            if (bbox) {
                size_t base = (size_t)b * 4 * h * w + id;
                float sx = (float)w * ds, sy = (float)h * ds;
                t0 = bbox[base]                     * sx;
                t1 = bbox[base + (size_t)h * w]     * sy;
                t2 = bbox[base + (size_t)2 * h * w] * sx;
                t3 = bbox[base + (size_t)3 * h * w] * sy;
            }
            float bx = xc + t0, by = yc + t1;
            o0 = bx - 0.5f * t2;
            o1 = by - 0.5f * t3;
            o2 = bx + 0.5f * t2;
            o3 = by + 0.5f * t3;
        }
        float* op = out + ((size_t)b * KTOP + j) * 5;
        op[0] = o0; op[1] = o1; op[2] = o2; op[3] = o3; op[4] = val;
    }
}

// ---- launch -----------------------------------------------------------------
extern "C" void kernel_launch(void* const* d_in, const int* in_sizes, int n_in,
                              void* d_out, int out_size, void* d_ws, size_t ws_size,
                              hipStream_t stream) {
    const float* pmap  = (const float*)d_in[0];   // [64,2,68,120]
    const float* pbbox = (const float*)d_in[1];   // [64,4,68,120]
    const float* bmap  = (const float*)d_in[2];   // [64,2,272,480]
    float* out = (float*)d_out;                   // player [64,100,5] then ball [64,100,5]

    const int B = 64;
    const int HP = 68, WP = 120, HB = 272, WB = 480;
    const int P_SLICES = 4, B_SLICES = 16, SLICE_ROWS = 17;
    const int P_CAP = 1024, B_CAP = 2048;         // survivors/slice ~227 / ~907

    uint64_t* ws_pkey = (uint64_t*)d_ws;                       // 64*4*128 u64
    uint64_t* ws_bkey = ws_pkey + (size_t)B * P_SLICES * KSLICE; // 64*16*128 u64

    size_t lds_p1 = (size_t)(SLICE_ROWS + 2) * WP * 4 + (size_t)P_CAP * 8;
    stage1<<<dim3(P_SLICES, B), TPB, lds_p1, stream>>>(pmap, HP, WP, SLICE_ROWS,
                                                       P_SLICES, P_CAP, ws_pkey);

    size_t lds_b1 = (size_t)(SLICE_ROWS + 2) * WB * 4 + (size_t)B_CAP * 8;
    stage1<<<dim3(B_SLICES, B), TPB, lds_b1, stream>>>(bmap, HB, WB, SLICE_ROWS,
                                                       B_SLICES, B_CAP, ws_bkey);

    stage2<<<B, TPB, (size_t)(P_SLICES * KSLICE) * 8, stream>>>(
        pbbox, HP, WP, P_SLICES * KSLICE, 16.0f, 0.0f, ws_pkey, out);
    stage2<<<B, TPB, (size_t)(B_SLICES * KSLICE) * 8, stream>>>(
        nullptr, HB, WB, B_SLICES * KSLICE, 4.0f, 40.0f, ws_bkey,
        out + (size_t)B * KTOP * 5);
}

// Round 4
// 201.972 us; speedup vs baseline: 3.5655x; 3.1831x over previous
//
#include <hip/hip_runtime.h>
#include <stdint.h>
#include <math.h>

#define TPB 256
#define KTOP 100
#define K1   128     // stage-1 per-slice selection target
#define KSLOT 256    // per-slice emitted candidate slots

// ============================================================================
// np-f32 softmax positive channel is a MONOTONE function G of D = fl32(x1-x0)
// (bit-identical to the round-2-validated emulation of the numpy mirror):
//   t = -|D|; et = f32(exp_f64(t));  D>0: p=1/(et+1)  else: p=et/(1+et)
// Ordering by D == ordering by p, except G may collapse distinct D to equal p;
// collapse needs |dD| < ~6e-8 * e^|D|  (< 0.25 for |D| < 15).
// ============================================================================
__device__ __forceinline__ float G_exact(float D) {
    float t = -fabsf(D);
    float etf = (float)exp((double)t);       // correctly-rounded f32 exp
    return (D > 0.0f) ? __fdiv_rn(1.0f, __fadd_rn(etf, 1.0f))
                      : __fdiv_rn(etf, __fadd_rn(1.0f, etf));
}

// Order-preserving f32 -> u32 (handles negatives), and its inverse.
__device__ __forceinline__ uint32_t flip_f32(float D) {
    uint32_t u = __float_as_uint(D);
    return (u & 0x80000000u) ? ~u : (u | 0x80000000u);
}
__device__ __forceinline__ float unflip_f32(uint32_t k) {
    uint32_t u = (k & 0x80000000u) ? (k ^ 0x80000000u) : ~k;
    return __uint_as_float(u);
}

// key = (orderbits << 32) | ~idx : descending sort => value desc, idx asc.
__device__ __forceinline__ uint64_t make_key(uint32_t orderbits, int idx) {
    return ((uint64_t)orderbits << 32) | (uint32_t)(~idx);
}

// In-place suffix-sum of 256 u32 bins: hist[i] <- sum_{j>=i} hist[j].
// One wave does the work via shuffles (no extra barriers inside).
__device__ __forceinline__ void suffix_scan_256(uint32_t* hist) {
    if (threadIdx.x < 64) {
        int lane = threadIdx.x;
        uint32_t h0 = hist[4*lane+0], h1 = hist[4*lane+1];
        uint32_t h2 = hist[4*lane+2], h3 = hist[4*lane+3];
        uint32_t tot = h0 + h1 + h2 + h3;
        uint32_t run = tot;
        #pragma unroll
        for (int d = 1; d < 64; d <<= 1) {
            uint32_t o = __shfl_down(run, d, 64);
            if (lane + d < 64) run += o;
        }
        uint32_t ab = run - tot;             // sum over lanes > lane
        hist[4*lane+3] = ab + h3;
        hist[4*lane+2] = ab + h3 + h2;
        hist[4*lane+1] = ab + h3 + h2 + h1;
        hist[4*lane+0] = ab + tot;
    }
    __syncthreads();
}

// In-LDS bitonic sort on u64 keys, descending. N = power of two (used at 256).
__device__ void bitonic_sort(uint64_t* keys, int N) {
    for (int k = 2; k <= N; k <<= 1) {
        for (int j = k >> 1; j > 0; j >>= 1) {
            for (int i = threadIdx.x; i < N; i += TPB) {
                int ixj = i ^ j;
                if (ixj > i) {
                    uint64_t ka = keys[i], kb = keys[ixj];
                    bool sw = ((ka < kb) == ((i & k) == 0));
                    if (sw) { keys[i] = kb; keys[ixj] = ka; }
                }
            }
            __syncthreads();
        }
    }
}

// 6-wide row window [c4-1 .. c4+4] from the LDS D-tile (OOB -> -inf).
__device__ __forceinline__ void row6(const float* df, int w, int row, int c4, float* a) {
    const float4 m = ((const float4*)df)[(row * w + c4) >> 2];
    a[1] = m.x; a[2] = m.y; a[3] = m.z; a[4] = m.w;
    a[0] = (c4 > 0)     ? df[row * w + c4 - 1] : -INFINITY;
    a[5] = (c4 + 4 < w) ? df[row * w + c4 + 4] : -INFINITY;
}

// ---- stage 1: D-tile NMS + histogram-select top~128, emit <=256 keys -------
__global__ void stage1(const float* __restrict__ x, int h, int w,
                       int sliceRows, int nSlices, int cap,
                       uint64_t* __restrict__ key_out)
{
    const int s = blockIdx.x;
    const int b = blockIdx.y;
    const int r0 = s * sliceRows;
    const int r1 = min(r0 + sliceRows, h);
    const int tileRows = sliceRows + 2;
    const int w4 = w >> 2;

    extern __shared__ unsigned char smem[];
    float*    df   = (float*)smem;                                    // tileRows*w
    uint64_t* keys = (uint64_t*)(smem + (size_t)tileRows * w * 4);    // cap
    uint32_t* hist = (uint32_t*)(keys + cap);                         // 256
    uint64_t* outb = (uint64_t*)(hist + 256);                         // 256
    __shared__ int s_cnt, s_out;
    __shared__ uint32_t s_bin, s_ab, s_none;
    if (threadIdx.x == 0) { s_cnt = 0; s_out = 0; s_none = 0; }

    const float*  x0  = x + (size_t)b * 2 * h * w;
    const float*  x1  = x0 + (size_t)h * w;
    const float4* x0v = (const float4*)x0;
    const float4* x1v = (const float4*)x1;
    float4* dfv = (float4*)df;

    // Load D = fl(x1-x0) tile, float4-vectorized; OOB rows -> -inf.
    const int nt4 = tileRows * w4;
    for (int t = threadIdx.x; t < nt4; t += TPB) {
        int tr = t / w4, c4 = t - tr * w4;
        int r = r0 - 1 + tr;
        float4 d4 = make_float4(-INFINITY, -INFINITY, -INFINITY, -INFINITY);
        if (r >= 0 && r < h) {
            float4 a = x0v[r * w4 + c4];
            float4 c = x1v[r * w4 + c4];
            d4.x = __fsub_rn(c.x, a.x);
            d4.y = __fsub_rn(c.y, a.y);
            d4.z = __fsub_rn(c.z, a.z);
            d4.w = __fsub_rn(c.w, a.w);
        }
        dfv[t] = d4;
    }
    __syncthreads();

    // NMS, 4 cells per iteration via 6-wide row windows.
    const int groups = (r1 - r0) * w4;
    for (int g = threadIdx.x; g < groups; g += TPB) {
        int lr = g / w4, c4 = (g - lr * w4) << 2;
        int tr = lr + 1;
        float ap[6], ac[6], an[6];
        row6(df, w, tr - 1, c4, ap);
        row6(df, w, tr,     c4, ac);
        row6(df, w, tr + 1, c4, an);
        #pragma unroll
        for (int j = 0; j < 4; ++j) {
            float v = ac[j + 1];
            float mx = fmaxf(fmaxf(fmaxf(ap[j], ap[j+1]), fmaxf(ap[j+2], an[j])),
                             fmaxf(fmaxf(an[j+1], an[j+2]), fmaxf(ac[j], ac[j+2])));
            bool keep;
            if (v >= mx) keep = true;                              // exact
            else if (mx - v >= 0.25f && mx < 13.0f) keep = false;  // G provably distinct
            else keep = (G_exact(v) == G_exact(mx));               // rare tie check
            if (keep) {
                int pos = atomicAdd(&s_cnt, 1);
                if (pos < cap)
                    keys[pos] = make_key(flip_f32(v), (r0 + lr) * w + c4 + j);
            }
        }
    }
    hist[threadIdx.x] = 0;
    __syncthreads();

    const int n = min(s_cnt, cap);

    // Level 1: histogram of flipD byte3 (key bits 56..63).
    for (int t = threadIdx.x; t < n; t += TPB)
        atomicAdd(&hist[(uint32_t)(keys[t] >> 56)], 1u);
    __syncthreads();
    suffix_scan_256(hist);
    {
        uint32_t si = hist[threadIdx.x];
        uint32_t sn = (threadIdx.x < 255) ? hist[threadIdx.x + 1] : 0;
        if (threadIdx.x == 0 && si < K1) s_none = 1;
        if (si >= K1 && sn < K1) { s_bin = threadIdx.x; s_ab = sn; }
    }
    __syncthreads();

    uint32_t T16 = 0;
    if (!s_none) {
        uint32_t b3 = s_bin, k2 = K1 - s_ab;
        hist[threadIdx.x] = 0;
        __syncthreads();
        // Level 2: byte2 among keys whose byte3 == b3.
        for (int t = threadIdx.x; t < n; t += TPB) {
            uint64_t k = keys[t];
            if ((uint32_t)(k >> 56) == b3)
                atomicAdd(&hist[(uint32_t)(k >> 48) & 255u], 1u);
        }
        __syncthreads();
        suffix_scan_256(hist);
        {
            uint32_t si = hist[threadIdx.x];
            uint32_t sn = (threadIdx.x < 255) ? hist[threadIdx.x + 1] : 0;
            if (si >= k2 && sn < k2) s_bin = threadIdx.x;
        }
        __syncthreads();
        T16 = (b3 << 8) | s_bin;
    }

    // Compact all survivors with top-16 D-key bits >= T16 (unsorted).
    outb[threadIdx.x] = 0;
    __syncthreads();
    for (int t = threadIdx.x; t < n; t += TPB) {
        uint64_t k = keys[t];
        if ((uint32_t)(k >> 48) >= T16) {
            int pos = atomicAdd(&s_out, 1);
            if (pos < KSLOT) outb[pos] = k;
        }
    }
    __syncthreads();
    key_out[((size_t)(b * nSlices + s)) * KSLOT + threadIdx.x] = outb[threadIdx.x];
}

// ---- stage 2: exact-p radix-select top-100 + tiny sort + decode ------------
__global__ void stage2(const float* __restrict__ bbox, int h, int w, int M,
                       float ds, float fixedSize,
                       const uint64_t* __restrict__ key_in, float* __restrict__ out)
{
    const int b = blockIdx.x;
    extern __shared__ unsigned char smem[];
    uint64_t* keys = (uint64_t*)smem;           // M
    uint32_t* hist = (uint32_t*)(keys + M);     // 256
    uint64_t* outb = (uint64_t*)(hist + 256);   // 256
    __shared__ int s_out;
    __shared__ uint32_t s_bin, s_ab;
    if (threadIdx.x == 0) s_out = 0;

    // Re-key candidates by exact np p-bits (high) | ~idx (low).
    for (int t = threadIdx.x; t < M; t += TPB) {
        uint64_t kin = key_in[(size_t)b * M + t];
        uint64_t u = 0;
        if (kin != 0) {
            float D = unflip_f32((uint32_t)(kin >> 32));
            float p = G_exact(D);
            u = ((uint64_t)__float_as_uint(p) << 32) | (uint32_t)kin;
        }
        keys[t] = u;
    }
    __syncthreads();

    // 4-level radix select: T = exact p32 of the KTOP-th largest (w/ dups).
    uint32_t prefix = 0, Kcur = KTOP;
    for (int lvl = 3; lvl >= 0; --lvl) {
        uint32_t msk = (lvl == 3) ? 0u : (0xFFFFFFFFu << ((lvl + 1) * 8));
        hist[threadIdx.x] = 0;
        __syncthreads();
        for (int t = threadIdx.x; t < M; t += TPB) {
            uint64_t k = keys[t];
            if (k) {
                uint32_t p = (uint32_t)(k >> 32);
                if ((p & msk) == prefix)
                    atomicAdd(&hist[(p >> (8 * lvl)) & 255u], 1u);
            }
        }
        __syncthreads();
        suffix_scan_256(hist);
        {
            uint32_t si = hist[threadIdx.x];
            uint32_t sn = (threadIdx.x < 255) ? hist[threadIdx.x + 1] : 0;
            if (si >= Kcur && sn < Kcur) { s_bin = threadIdx.x; s_ab = sn; }
        }
        __syncthreads();
        prefix |= s_bin << (8 * lvl);
        Kcur -= s_ab;
        __syncthreads();
    }
    const uint32_t T = prefix;

    // Compact all with p32 >= T (count in [100, ~110]; cap 256), then sort.
    outb[threadIdx.x] = 0;
    __syncthreads();
    for (int t = threadIdx.x; t < M; t += TPB) {
        uint64_t k = keys[t];
        if (k && (uint32_t)(k >> 32) >= T) {
            int pos = atomicAdd(&s_out, 1);
            if (pos < 256) outb[pos] = k;
        }
    }
    __syncthreads();
    bitonic_sort(outb, 256);

    // Decode top-100.
    for (int j = threadIdx.x; j < KTOP; j += TPB) {
        uint64_t k = outb[j];
        int id = (int)(~(uint32_t)k);
        float o0 = 0.f, o1 = 0.f, o2 = 0.f, o3 = 0.f, val = 0.f;
        if ((unsigned)id < (unsigned)(h * w)) {
            val = __uint_as_float((uint32_t)(k >> 32));
            int yy = id / w, xx = id - yy * w;
            float xc = (float)xx * ds + (ds - 1.0f) * 0.5f;
            float yc = (float)yy * ds + (ds - 1.0f) * 0.5f;
            float t0 = 0.f, t1 = 0.f, t2 = fixedSize, t3 = fixedSize;
            if (bbox) {
                size_t base = (size_t)b * 4 * h * w + id;
                float sx = (float)w * ds, sy = (float)h * ds;
                t0 = bbox[base]                     * sx;
                t1 = bbox[base + (size_t)h * w]     * sy;
                t2 = bbox[base + (size_t)2 * h * w] * sx;
                t3 = bbox[base + (size_t)3 * h * w] * sy;
            }
            float bx = xc + t0, by = yc + t1;
            o0 = bx - 0.5f * t2;
            o1 = by - 0.5f * t3;
            o2 = bx + 0.5f * t2;
            o3 = by + 0.5f * t3;
        }
        float* op = out + ((size_t)b * KTOP + j) * 5;
        op[0] = o0; op[1] = o1; op[2] = o2; op[3] = o3; op[4] = val;
    }
}

// ---- launch -----------------------------------------------------------------
extern "C" void kernel_launch(void* const* d_in, const int* in_sizes, int n_in,
                              void* d_out, int out_size, void* d_ws, size_t ws_size,
                              hipStream_t stream) {
    const float* pmap  = (const float*)d_in[0];   // [64,2,68,120]
    const float* pbbox = (const float*)d_in[1];   // [64,4,68,120]
    const float* bmap  = (const float*)d_in[2];   // [64,2,272,480]
    float* out = (float*)d_out;                   // player [64,100,5] then ball [64,100,5]

    const int B = 64;
    const int HP = 68, WP = 120, HB = 272, WB = 480;
    const int P_SLICES = 4, B_SLICES = 16, SLICE_ROWS = 17;
    const int P_CAP = 1024, B_CAP = 2048;         // survivors/slice ~227 / ~907

    uint64_t* ws_pkey = (uint64_t*)d_ws;                          // 64*4*256 u64
    uint64_t* ws_bkey = ws_pkey + (size_t)B * P_SLICES * KSLOT;   // 64*16*256 u64

    size_t lds_p1 = (size_t)(SLICE_ROWS + 2) * WP * 4 + (size_t)P_CAP * 8 + 1024 + 2048;
    stage1<<<dim3(P_SLICES, B), TPB, lds_p1, stream>>>(pmap, HP, WP, SLICE_ROWS,
                                                       P_SLICES, P_CAP, ws_pkey);

    size_t lds_b1 = (size_t)(SLICE_ROWS + 2) * WB * 4 + (size_t)B_CAP * 8 + 1024 + 2048;
    stage1<<<dim3(B_SLICES, B), TPB, lds_b1, stream>>>(bmap, HB, WB, SLICE_ROWS,
                                                       B_SLICES, B_CAP, ws_bkey);

    stage2<<<B, TPB, (size_t)(P_SLICES * KSLOT) * 8 + 1024 + 2048, stream>>>(
        pbbox, HP, WP, P_SLICES * KSLOT, 16.0f, 0.0f, ws_pkey, out);
    stage2<<<B, TPB, (size_t)(B_SLICES * KSLOT) * 8 + 1024 + 2048, stream>>>(
        nullptr, HB, WB, B_SLICES * KSLOT, 4.0f, 40.0f, ws_bkey,
        out + (size_t)B * KTOP * 5);
}

// Round 5
// 159.237 us; speedup vs baseline: 4.5224x; 1.2684x over previous
//
#include <hip/hip_runtime.h>
#include <stdint.h>
#include <math.h>

#define TPB   256
#define KTOP  100
#define K1    128    // selection rank cut (per-slice in s1, pre-cut in s2)
#define KSLOT 192    // per-slice emitted u32 slots (>= K1 + tie-bin margin)
#define CAP   1024   // stage-1 survivor capacity (expected ~430/slice max)
#define SR    8      // slice rows

#define HB 272
#define WB 480
#define NSB 34       // 272/8
#define HP 68
#define WP 120
#define NSP 9        // ceil(68/8), last slice 4 rows
#define NB 64

// ============================================================================
// Validated invariants (rounds 2-4, absmax 0.0):
//  - np-f32 softmax p is a MONOTONE function G of D = fl32(x1-x0);
//    G collapse window |dD| < ~6e-8*e^|D| (< 0.25 for |D| < 13).
//  - NMS: keep iff p >= all 8 neighbors; D-space fast path + exact G on ties.
//  - top-k tie order: (p desc, idx asc)  ==  u64 key (p_bits<<32 | ~idx) desc.
//  - 16-bit D-key rank-128 cut contains the exact top-100 set (margin >> any
//    p-tie group size; bins near the cut hold ~2-10 elements).
// ============================================================================
__device__ __forceinline__ float G_exact(float D) {
    float t = -fabsf(D);
    float etf = (float)exp((double)t);       // correctly-rounded f32 exp
    return (D > 0.0f) ? __fdiv_rn(1.0f, __fadd_rn(etf, 1.0f))
                      : __fdiv_rn(etf, __fadd_rn(1.0f, etf));
}

__device__ __forceinline__ uint32_t flip_f32(float D) {
    uint32_t u = __float_as_uint(D);
    return (u & 0x80000000u) ? ~u : (u | 0x80000000u);
}

// In-place suffix-sum of 256 u32 bins: hist[i] <- sum_{j>=i} hist[j].
// Wave 0 via shuffles; ends with a barrier. (validated round 4)
__device__ __forceinline__ void suffix_scan_256(uint32_t* hist) {
    if (threadIdx.x < 64) {
        int lane = threadIdx.x;
        uint32_t h0 = hist[4*lane+0], h1 = hist[4*lane+1];
        uint32_t h2 = hist[4*lane+2], h3 = hist[4*lane+3];
        uint32_t tot = h0 + h1 + h2 + h3;
        uint32_t run = tot;
        #pragma unroll
        for (int d = 1; d < 64; d <<= 1) {
            uint32_t o = __shfl_down(run, d, 64);
            if (lane + d < 64) run += o;
        }
        uint32_t ab = run - tot;
        hist[4*lane+3] = ab + h3;
        hist[4*lane+2] = ab + h3 + h2;
        hist[4*lane+1] = ab + h3 + h2 + h1;
        hist[4*lane+0] = ab + tot;
    }
    __syncthreads();
}

// Descending bitonic sort of 256 u64 keys, 1 elem/thread. (validated round 4)
__device__ void bitonic_sort_256(uint64_t* keys) {
    for (int k = 2; k <= 256; k <<= 1) {
        for (int j = k >> 1; j > 0; j >>= 1) {
            int i = threadIdx.x;
            int ixj = i ^ j;
            if (ixj > i) {
                uint64_t ka = keys[i], kb = keys[ixj];
                bool sw = ((ka < kb) == ((i & k) == 0));
                if (sw) { keys[i] = kb; keys[ixj] = ka; }
            }
            __syncthreads();
        }
    }
}

// 6-wide row window [c4-1 .. c4+4] from the LDS D-tile (OOB -> -inf).
__device__ __forceinline__ void row6(const float* df, int w, int row, int c4, float* a) {
    const float4 m = ((const float4*)df)[(row * w + c4) >> 2];
    a[1] = m.x; a[2] = m.y; a[3] = m.z; a[4] = m.w;
    a[0] = (c4 > 0)     ? df[row * w + c4 - 1] : -INFINITY;
    a[5] = (c4 + 4 < w) ? df[row * w + c4 + 4] : -INFINITY;
}

// ---- stage 1 (fused ball+player): NMS + D16 radix-select, emit u32 slots ---
__global__ __launch_bounds__(TPB) void stage1(const float* __restrict__ bmap,
                                              const float* __restrict__ pmap,
                                              uint32_t* __restrict__ bkey,
                                              uint32_t* __restrict__ pkey)
{
    const bool isBall = blockIdx.x < NSB;
    const float* x; int h, w, s, nS; uint32_t* key_out;
    if (isBall) { x = bmap; h = HB; w = WB; s = blockIdx.x;       key_out = bkey; nS = NSB; }
    else        { x = pmap; h = HP; w = WP; s = blockIdx.x - NSB; key_out = pkey; nS = NSP; }
    const int b = blockIdx.y;
    const int r0 = s * SR;
    const int r1 = min(r0 + SR, h);
    const int w4 = w >> 2;
    const int tileRows = SR + 2;

    extern __shared__ unsigned char smem[];
    float*    df   = (float*)smem;                    // tileRows * w
    uint32_t* surv = (uint32_t*)(df + tileRows * w);  // CAP
    uint32_t* hist = surv + CAP;                      // 256
    uint32_t* outb = hist + 256;                      // KSLOT
    __shared__ int s_cnt, s_out;
    __shared__ uint32_t s_bin, s_ab, s_bin2, s_none;
    if (threadIdx.x == 0) { s_cnt = 0; s_out = 0; s_none = 0; }
    hist[threadIdx.x] = 0;

    const float*  x0  = x + (size_t)b * 2 * h * w;
    const float*  x1  = x0 + (size_t)h * w;
    const float4* x0v = (const float4*)x0;
    const float4* x1v = (const float4*)x1;
    float4* dfv = (float4*)df;

    // D tile (rows r0-1 .. r0+SR), float4-vectorized; OOB rows -> -inf.
    const int nt4 = tileRows * w4;
    for (int t = threadIdx.x; t < nt4; t += TPB) {
        int tr = t / w4, c4 = t - tr * w4;
        int r = r0 - 1 + tr;
        float4 d4 = make_float4(-INFINITY, -INFINITY, -INFINITY, -INFINITY);
        if (r >= 0 && r < h) {
            float4 a = x0v[r * w4 + c4];
            float4 c = x1v[r * w4 + c4];
            d4.x = __fsub_rn(c.x, a.x);
            d4.y = __fsub_rn(c.y, a.y);
            d4.z = __fsub_rn(c.z, a.z);
            d4.w = __fsub_rn(c.w, a.w);
        }
        dfv[t] = d4;
    }
    __syncthreads();

    // NMS (4 cells/iter) + level-1 histogram fused into the keep path.
    const int groups = (r1 - r0) * w4;
    for (int g = threadIdx.x; g < groups; g += TPB) {
        int lr = g / w4, c4 = (g - lr * w4) << 2;
        int tr = lr + 1;
        float ap[6], ac[6], an[6];
        row6(df, w, tr - 1, c4, ap);
        row6(df, w, tr,     c4, ac);
        row6(df, w, tr + 1, c4, an);
        #pragma unroll
        for (int j = 0; j < 4; ++j) {
            float v = ac[j + 1];
            float mx = fmaxf(fmaxf(fmaxf(ap[j], ap[j+1]), fmaxf(ap[j+2], an[j])),
                             fmaxf(fmaxf(an[j+1], an[j+2]), fmaxf(ac[j], ac[j+2])));
            bool keep;
            if (v >= mx) keep = true;                              // exact
            else if (mx - v >= 0.25f && mx < 13.0f) keep = false;  // G distinct
            else keep = (G_exact(v) == G_exact(mx));               // rare tie
            if (keep) {
                uint32_t key16 = flip_f32(v) >> 16;
                int pos = atomicAdd(&s_cnt, 1);
                if (pos < CAP)
                    surv[pos] = (key16 << 16) | ((uint32_t)lr << 9) | (uint32_t)(c4 + j);
                atomicAdd(&hist[key16 >> 8], 1u);
            }
        }
    }
    __syncthreads();
    const int n = min(s_cnt, CAP);

    // Level-1 select on D16 high byte.
    suffix_scan_256(hist);
    {
        uint32_t si = hist[threadIdx.x];
        uint32_t sn = (threadIdx.x < 255) ? hist[threadIdx.x + 1] : 0u;
        if (threadIdx.x == 0 && hist[0] < K1) s_none = 1;
        if (si >= K1 && sn < K1) { s_bin = threadIdx.x; s_ab = sn; }
    }
    __syncthreads();

    uint32_t T16 = 0;
    if (!s_none) {
        const uint32_t b3 = s_bin;
        const uint32_t k2 = K1 - s_ab;
        hist[threadIdx.x] = 0;
        __syncthreads();
        for (int t = threadIdx.x; t < n; t += TPB) {
            uint32_t sv = surv[t];
            if ((sv >> 24) == b3) atomicAdd(&hist[(sv >> 16) & 255u], 1u);
        }
        __syncthreads();
        suffix_scan_256(hist);
        {
            uint32_t si = hist[threadIdx.x];
            uint32_t sn = (threadIdx.x < 255) ? hist[threadIdx.x + 1] : 0u;
            if (si >= k2 && sn < k2) s_bin2 = threadIdx.x;
        }
        __syncthreads();
        T16 = (b3 << 8) | s_bin2;
    }

    // Compact survivors with D16 >= T16 (unsorted), zero-padded to KSLOT.
    if (threadIdx.x < KSLOT) outb[threadIdx.x] = 0;
    __syncthreads();
    for (int t = threadIdx.x; t < n; t += TPB) {
        uint32_t sv = surv[t];
        if ((sv >> 16) >= T16) {
            int pos = atomicAdd(&s_out, 1);
            if (pos < KSLOT) outb[pos] = sv;
        }
    }
    __syncthreads();
    if (threadIdx.x < KSLOT)
        key_out[((size_t)b * nS + s) * KSLOT + threadIdx.x] = outb[threadIdx.x];
}

// ---- stage 2 (fused): D16 select -> exact-p re-rank of <=256 -> decode -----
__global__ __launch_bounds__(TPB) void stage2(const float* __restrict__ bmap,
                                              const float* __restrict__ pmap,
                                              const float* __restrict__ pbbox,
                                              const uint32_t* __restrict__ bkey,
                                              const uint32_t* __restrict__ pkey,
                                              float* __restrict__ out)
{
    const bool isBall = blockIdx.x < NB;
    int b, M, h, w;
    const uint32_t* kin; const float* xmap; const float* bbox;
    float ds, fixedSize; float* outp;
    if (isBall) {
        b = blockIdx.x; M = NSB * KSLOT; h = HB; w = WB;
        kin = bkey + (size_t)b * M; xmap = bmap; bbox = nullptr;
        ds = 4.0f; fixedSize = 40.0f;
        outp = out + (size_t)NB * KTOP * 5 + (size_t)b * KTOP * 5;
    } else {
        b = blockIdx.x - NB; M = NSP * KSLOT; h = HP; w = WP;
        kin = pkey + (size_t)b * M; xmap = pmap;
        bbox = pbbox + (size_t)b * 4 * HP * WP;
        ds = 16.0f; fixedSize = 0.0f;
        outp = out + (size_t)b * KTOP * 5;
    }
    const float* x0 = xmap + (size_t)b * 2 * h * w;
    const float* x1 = x0 + (size_t)h * w;

    extern __shared__ unsigned char smem[];
    uint32_t* keys = (uint32_t*)smem;           // M
    uint32_t* hist = keys + M;                  // 256
    uint64_t* outb = (uint64_t*)(hist + 256);   // 256
    __shared__ int s_out;
    __shared__ uint32_t s_bin, s_ab, s_bin2, s_none;
    if (threadIdx.x == 0) { s_out = 0; s_none = 0; }
    hist[threadIdx.x] = 0;
    __syncthreads();

    // Load keys + level-1 histogram in one pass.
    for (int t = threadIdx.x; t < M; t += TPB) {
        uint32_t k = kin[t];
        keys[t] = k;
        if (k) atomicAdd(&hist[k >> 24], 1u);
    }
    __syncthreads();
    suffix_scan_256(hist);
    {
        uint32_t si = hist[threadIdx.x];
        uint32_t sn = (threadIdx.x < 255) ? hist[threadIdx.x + 1] : 0u;
        if (threadIdx.x == 0 && hist[0] < K1) s_none = 1;
        if (si >= K1 && sn < K1) { s_bin = threadIdx.x; s_ab = sn; }
    }
    __syncthreads();

    uint32_t T16 = 0;
    if (!s_none) {
        const uint32_t b3 = s_bin;
        const uint32_t k2 = K1 - s_ab;
        hist[threadIdx.x] = 0;
        __syncthreads();
        for (int t = threadIdx.x; t < M; t += TPB) {
            uint32_t k = keys[t];
            if (k && (k >> 24) == b3) atomicAdd(&hist[(k >> 16) & 255u], 1u);
        }
        __syncthreads();
        suffix_scan_256(hist);
        {
            uint32_t si = hist[threadIdx.x];
            uint32_t sn = (threadIdx.x < 255) ? hist[threadIdx.x + 1] : 0u;
            if (si >= k2 && sn < k2) s_bin2 = threadIdx.x;
        }
        __syncthreads();
        T16 = (b3 << 8) | s_bin2;
    }

    // Compact finalists; compute exact np p only here (D re-read from map).
    outb[threadIdx.x] = 0;
    __syncthreads();
    for (int t = threadIdx.x; t < M; t += TPB) {
        uint32_t k = keys[t];
        if (k && (k >> 16) >= T16) {
            int pos = atomicAdd(&s_out, 1);
            if (pos < 256) {
                int sIdx = t / KSLOT;
                int lr = (k >> 9) & 7, c = k & 511;
                int gidx = (sIdx * SR + lr) * w + c;
                float D = __fsub_rn(x1[gidx], x0[gidx]);
                float p = G_exact(D);
                outb[pos] = ((uint64_t)__float_as_uint(p) << 32) | (uint32_t)(~gidx);
            }
        }
    }
    __syncthreads();
    bitonic_sort_256(outb);

    // Decode top-100 (exact (p desc, idx asc) order).
    if (threadIdx.x < KTOP) {
        uint64_t k = outb[threadIdx.x];
        int id = (int)(~(uint32_t)k);
        float o0 = 0.f, o1 = 0.f, o2 = 0.f, o3 = 0.f, val = 0.f;
        if ((unsigned)id < (unsigned)(h * w)) {
            val = __uint_as_float((uint32_t)(k >> 32));
            int yy = id / w, xx = id - yy * w;
            float xc = (float)xx * ds + (ds - 1.0f) * 0.5f;
            float yc = (float)yy * ds + (ds - 1.0f) * 0.5f;
            float t0 = 0.f, t1 = 0.f, t2 = fixedSize, t3 = fixedSize;
            if (bbox) {
                float sx = (float)w * ds, sy = (float)h * ds;
                t0 = bbox[id]                 * sx;
                t1 = bbox[id + h * w]         * sy;
                t2 = bbox[id + 2 * h * w]     * sx;
                t3 = bbox[id + 3 * h * w]     * sy;
            }
            float bx = xc + t0, by = yc + t1;
            o0 = bx - 0.5f * t2;
            o1 = by - 0.5f * t3;
            o2 = bx + 0.5f * t2;
            o3 = by + 0.5f * t3;
        }
        float* op = outp + (size_t)threadIdx.x * 5;
        op[0] = o0; op[1] = o1; op[2] = o2; op[3] = o3; op[4] = val;
    }
}

// ---- launch -----------------------------------------------------------------
extern "C" void kernel_launch(void* const* d_in, const int* in_sizes, int n_in,
                              void* d_out, int out_size, void* d_ws, size_t ws_size,
                              hipStream_t stream) {
    const float* pmap  = (const float*)d_in[0];   // [64,2,68,120]
    const float* pbbox = (const float*)d_in[1];   // [64,4,68,120]
    const float* bmap  = (const float*)d_in[2];   // [64,2,272,480]
    float* out = (float*)d_out;                   // player [64,100,5] then ball

    uint32_t* ws_bkey = (uint32_t*)d_ws;                       // 64*34*192 u32
    uint32_t* ws_pkey = ws_bkey + (size_t)NB * NSB * KSLOT;    // 64*9*192 u32
    // total ws: 2,113,536 B (within proven budget)

    size_t lds1 = (size_t)(SR + 2) * WB * 4 + (size_t)CAP * 4 + 1024 + (size_t)KSLOT * 4; // 25088
    stage1<<<dim3(NSB + NSP, NB), TPB, lds1, stream>>>(bmap, pmap, ws_bkey, ws_pkey);

    size_t lds2 = (size_t)NSB * KSLOT * 4 + 1024 + 2048;       // 29184
    stage2<<<2 * NB, TPB, lds2, stream>>>(bmap, pmap, pbbox, ws_bkey, ws_pkey, out);
}

// Round 6
// 140.774 us; speedup vs baseline: 5.1155x; 1.1312x over previous
//
#include <hip/hip_runtime.h>
#include <stdint.h>
#include <math.h>

#define TPB   512    // 8 waves/block -> 4 blocks/CU hits the 32-wave cap
#define KTOP  100
#define K1    128    // selection rank cut (per-slice in s1, per-image in s2)
#define KSLOT 192    // per-slice emitted u32 slots (>= K1 + tie-bin margin)
#define CAP   768    // stage-1 survivor capacity (expected ~450/slice, +13 sigma)
#define SR    8      // slice rows

#define HB 272
#define WB 480
#define NSB 34       // 272/8
#define HP 68
#define WP 120
#define NSP 9        // ceil(68/8), last slice 4 rows
#define NB 64

// ============================================================================
// Validated invariants (rounds 2-5, absmax 0.0):
//  - np-f32 softmax p is a MONOTONE function G of D = fl32(x1-x0);
//    G collapse window |dD| < ~6e-8*e^|D| (< 0.25 for |D| < 13).
//  - NMS: keep iff p >= all 8 neighbors; D-space fast path + exact G on ties.
//  - top-k tie order: (p desc, idx asc)  ==  u64 key (p_bits<<32 | ~idx) desc.
//  - 16-bit D-key rank-128 cut contains the exact top-100 set.
// ============================================================================
__device__ __forceinline__ float G_exact(float D) {
    float t = -fabsf(D);
    float etf = (float)exp((double)t);       // correctly-rounded f32 exp
    return (D > 0.0f) ? __fdiv_rn(1.0f, __fadd_rn(etf, 1.0f))
                      : __fdiv_rn(etf, __fadd_rn(1.0f, etf));
}

__device__ __forceinline__ uint32_t flip_f32(float D) {
    uint32_t u = __float_as_uint(D);
    return (u & 0x80000000u) ? ~u : (u | 0x80000000u);
}

// In-place suffix-sum of 256 u32 bins: hist[i] <- sum_{j>=i} hist[j].
// Wave 0 via shuffles; ends with a barrier. (validated round 4)
__device__ __forceinline__ void suffix_scan_256(uint32_t* hist) {
    if (threadIdx.x < 64) {
        int lane = threadIdx.x;
        uint32_t h0 = hist[4*lane+0], h1 = hist[4*lane+1];
        uint32_t h2 = hist[4*lane+2], h3 = hist[4*lane+3];
        uint32_t tot = h0 + h1 + h2 + h3;
        uint32_t run = tot;
        #pragma unroll
        for (int d = 1; d < 64; d <<= 1) {
            uint32_t o = __shfl_down(run, d, 64);
            if (lane + d < 64) run += o;
        }
        uint32_t ab = run - tot;
        hist[4*lane+3] = ab + h3;
        hist[4*lane+2] = ab + h3 + h2;
        hist[4*lane+1] = ab + h3 + h2 + h1;
        hist[4*lane+0] = ab + tot;
    }
    __syncthreads();
}

// Descending bitonic sort of 256 u64 keys; TPB may exceed 256 (guarded).
__device__ void bitonic_sort_256(uint64_t* keys) {
    for (int k = 2; k <= 256; k <<= 1) {
        for (int j = k >> 1; j > 0; j >>= 1) {
            int i = threadIdx.x;
            if (i < 256) {
                int ixj = i ^ j;
                if (ixj > i) {
                    uint64_t ka = keys[i], kb = keys[ixj];
                    bool sw = ((ka < kb) == ((i & k) == 0));
                    if (sw) { keys[i] = kb; keys[ixj] = ka; }
                }
            }
            __syncthreads();
        }
    }
}

// 6-wide row window [c4-1 .. c4+4] from the LDS D-tile (OOB -> -inf).
template<int W>
__device__ __forceinline__ void row6(const float* df, int row, int c4, float* a) {
    const float4 m = ((const float4*)df)[(row * W + c4) >> 2];
    a[1] = m.x; a[2] = m.y; a[3] = m.z; a[4] = m.w;
    a[0] = (c4 > 0)     ? df[row * W + c4 - 1] : -INFINITY;
    a[5] = (c4 + 4 < W) ? df[row * W + c4 + 4] : -INFINITY;
}

// ---- stage 1 body: NMS + D16 radix-select, emit u32 slots ------------------
// Templated W/H/NS -> all divisions become compile-time magic-mul/shift.
template<int H, int W, int NS>
__device__ __forceinline__ void stage1_impl(const float* __restrict__ x,
                                            int s, int b,
                                            uint32_t* __restrict__ key_out,
                                            unsigned char* smem)
{
    constexpr int W4 = W / 4;
    constexpr int tileRows = SR + 2;
    const int r0 = s * SR;
    const int rows = (H - r0 < SR) ? (H - r0) : SR;

    float*    df   = (float*)smem;                         // tileRows * W
    uint32_t* surv = (uint32_t*)(df + tileRows * W);       // CAP
    uint32_t* hist = surv + CAP;                           // 256
    uint32_t* outb = hist + 256;                           // KSLOT
    __shared__ int s_cnt, s_out;
    __shared__ uint32_t s_bin, s_ab, s_bin2, s_none;
    if (threadIdx.x == 0) { s_cnt = 0; s_out = 0; s_none = 0; }
    if (threadIdx.x < 256) hist[threadIdx.x] = 0;

    const float*  x0  = x + (size_t)b * 2 * H * W;
    const float*  x1  = x0 + (size_t)H * W;
    const float4* x0v = (const float4*)x0;
    const float4* x1v = (const float4*)x1;
    float4* dfv = (float4*)df;

    // D tile (rows r0-1 .. r0+SR), float4-vectorized; OOB rows -> -inf.
    constexpr int nt4 = tileRows * W4;
    for (int t = threadIdx.x; t < nt4; t += TPB) {
        int tr = t / W4, c4 = t - tr * W4;        // compile-time divisor
        int r = r0 - 1 + tr;
        float4 d4 = make_float4(-INFINITY, -INFINITY, -INFINITY, -INFINITY);
        if (r >= 0 && r < H) {
            float4 a = x0v[r * W4 + c4];
            float4 c = x1v[r * W4 + c4];
            d4.x = __fsub_rn(c.x, a.x);
            d4.y = __fsub_rn(c.y, a.y);
            d4.z = __fsub_rn(c.z, a.z);
            d4.w = __fsub_rn(c.w, a.w);
        }
        dfv[t] = d4;
    }
    __syncthreads();

    // NMS (4 cells/iter) + level-1 histogram fused into the keep path.
    const int groups = rows * W4;
    for (int g = threadIdx.x; g < groups; g += TPB) {
        int lr = g / W4, c4 = (g - lr * W4) << 2; // compile-time divisor
        int tr = lr + 1;
        float ap[6], ac[6], an[6];
        row6<W>(df, tr - 1, c4, ap);
        row6<W>(df, tr,     c4, ac);
        row6<W>(df, tr + 1, c4, an);
        #pragma unroll
        for (int j = 0; j < 4; ++j) {
            float v = ac[j + 1];
            float mx = fmaxf(fmaxf(fmaxf(ap[j], ap[j+1]), fmaxf(ap[j+2], an[j])),
                             fmaxf(fmaxf(an[j+1], an[j+2]), fmaxf(ac[j], ac[j+2])));
            bool keep;
            if (v >= mx) keep = true;                              // exact
            else if (mx - v >= 0.25f && mx < 13.0f) keep = false;  // G distinct
            else keep = (G_exact(v) == G_exact(mx));               // rare tie
            if (keep) {
                uint32_t key16 = flip_f32(v) >> 16;
                int pos = atomicAdd(&s_cnt, 1);
                if (pos < CAP)
                    surv[pos] = (key16 << 16) | ((uint32_t)lr << 9) | (uint32_t)(c4 + j);
                atomicAdd(&hist[key16 >> 8], 1u);
            }
        }
    }
    __syncthreads();
    const int n = (s_cnt < CAP) ? s_cnt : CAP;

    // Level-1 select on D16 high byte.
    suffix_scan_256(hist);
    if (threadIdx.x < 256) {
        uint32_t si = hist[threadIdx.x];
        uint32_t sn = (threadIdx.x < 255) ? hist[threadIdx.x + 1] : 0u;
        if (threadIdx.x == 0 && si < K1) s_none = 1;
        if (si >= K1 && sn < K1) { s_bin = threadIdx.x; s_ab = sn; }
    }
    __syncthreads();

    uint32_t T16 = 0;
    if (!s_none) {
        const uint32_t b3 = s_bin;
        const uint32_t k2 = K1 - s_ab;
        if (threadIdx.x < 256) hist[threadIdx.x] = 0;
        __syncthreads();
        for (int t = threadIdx.x; t < n; t += TPB) {
            uint32_t sv = surv[t];
            if ((sv >> 24) == b3) atomicAdd(&hist[(sv >> 16) & 255u], 1u);
        }
        __syncthreads();
        suffix_scan_256(hist);
        if (threadIdx.x < 256) {
            uint32_t si = hist[threadIdx.x];
            uint32_t sn = (threadIdx.x < 255) ? hist[threadIdx.x + 1] : 0u;
            if (si >= k2 && sn < k2) s_bin2 = threadIdx.x;
        }
        __syncthreads();
        T16 = (b3 << 8) | s_bin2;
    }

    // Compact survivors with D16 >= T16 (unsorted), zero-padded to KSLOT.
    if (threadIdx.x < KSLOT) outb[threadIdx.x] = 0;
    __syncthreads();
    for (int t = threadIdx.x; t < n; t += TPB) {
        uint32_t sv = surv[t];
        if ((sv >> 16) >= T16) {
            int pos = atomicAdd(&s_out, 1);
            if (pos < KSLOT) outb[pos] = sv;
        }
    }
    __syncthreads();
    if (threadIdx.x < KSLOT)
        key_out[((size_t)b * NS + s) * KSLOT + threadIdx.x] = outb[threadIdx.x];
}

__global__ __launch_bounds__(TPB) void stage1(const float* __restrict__ bmap,
                                              const float* __restrict__ pmap,
                                              uint32_t* __restrict__ bkey,
                                              uint32_t* __restrict__ pkey)
{
    extern __shared__ unsigned char smem[];
    if (blockIdx.x < NSB)
        stage1_impl<HB, WB, NSB>(bmap, blockIdx.x, blockIdx.y, bkey, smem);
    else
        stage1_impl<HP, WP, NSP>(pmap, blockIdx.x - NSB, blockIdx.y, pkey, smem);
}

// ---- stage 2 body: D16 select -> exact-p re-rank of <=256 -> decode --------
template<int H, int W, int NS, bool BALL>
__device__ __forceinline__ void stage2_impl(const float* __restrict__ xmap,
                                            const float* __restrict__ pbbox,
                                            const uint32_t* __restrict__ key_in,
                                            float* __restrict__ outp,
                                            int b, unsigned char* smem)
{
    constexpr int M = NS * KSLOT;
    const float* x0 = xmap + (size_t)b * 2 * H * W;
    const float* x1 = x0 + (size_t)H * W;
    const uint32_t* kin = key_in + (size_t)b * M;

    uint32_t* keys = (uint32_t*)smem;           // M
    uint32_t* hist = keys + M;                  // 256
    uint64_t* outb = (uint64_t*)(hist + 256);   // 256
    __shared__ int s_out;
    __shared__ uint32_t s_bin, s_ab, s_bin2, s_none;
    if (threadIdx.x == 0) { s_out = 0; s_none = 0; }
    if (threadIdx.x < 256) hist[threadIdx.x] = 0;
    __syncthreads();

    // Load keys + level-1 histogram in one pass.
    for (int t = threadIdx.x; t < M; t += TPB) {
        uint32_t k = kin[t];
        keys[t] = k;
        if (k) atomicAdd(&hist[k >> 24], 1u);
    }
    __syncthreads();
    suffix_scan_256(hist);
    if (threadIdx.x < 256) {
        uint32_t si = hist[threadIdx.x];
        uint32_t sn = (threadIdx.x < 255) ? hist[threadIdx.x + 1] : 0u;
        if (threadIdx.x == 0 && si < K1) s_none = 1;
        if (si >= K1 && sn < K1) { s_bin = threadIdx.x; s_ab = sn; }
    }
    __syncthreads();

    uint32_t T16 = 0;
    if (!s_none) {
        const uint32_t b3 = s_bin;
        const uint32_t k2 = K1 - s_ab;
        if (threadIdx.x < 256) hist[threadIdx.x] = 0;
        __syncthreads();
        for (int t = threadIdx.x; t < M; t += TPB) {
            uint32_t k = keys[t];
            if (k && (k >> 24) == b3) atomicAdd(&hist[(k >> 16) & 255u], 1u);
        }
        __syncthreads();
        suffix_scan_256(hist);
        if (threadIdx.x < 256) {
            uint32_t si = hist[threadIdx.x];
            uint32_t sn = (threadIdx.x < 255) ? hist[threadIdx.x + 1] : 0u;
            if (si >= k2 && sn < k2) s_bin2 = threadIdx.x;
        }
        __syncthreads();
        T16 = (b3 << 8) | s_bin2;
    }

    // Compact finalists; compute exact np p only here (D re-read from map).
    if (threadIdx.x < 256) outb[threadIdx.x] = 0;
    __syncthreads();
    for (int t = threadIdx.x; t < M; t += TPB) {
        uint32_t k = keys[t];
        if (k && (k >> 16) >= T16) {
            int pos = atomicAdd(&s_out, 1);
            if (pos < 256) {
                int sIdx = t / KSLOT;                      // compile-time divisor
                int lr = (k >> 9) & 7, c = k & 511;
                int gidx = (sIdx * SR + lr) * W + c;
                float D = __fsub_rn(x1[gidx], x0[gidx]);
                float p = G_exact(D);
                outb[pos] = ((uint64_t)__float_as_uint(p) << 32) | (uint32_t)(~gidx);
            }
        }
    }
    __syncthreads();
    bitonic_sort_256(outb);

    // Decode top-100 (exact (p desc, idx asc) order).
    if (threadIdx.x < KTOP) {
        uint64_t k = outb[threadIdx.x];
        int id = (int)(~(uint32_t)k);
        float o0 = 0.f, o1 = 0.f, o2 = 0.f, o3 = 0.f, val = 0.f;
        if ((unsigned)id < (unsigned)(H * W)) {
            val = __uint_as_float((uint32_t)(k >> 32));
            int yy = id / W, xx = id - yy * W;             // compile-time divisor
            constexpr float ds = BALL ? 4.0f : 16.0f;
            float xc = (float)xx * ds + (ds - 1.0f) * 0.5f;
            float yc = (float)yy * ds + (ds - 1.0f) * 0.5f;
            float t0 = 0.f, t1 = 0.f;
            float t2 = BALL ? 40.0f : 0.0f, t3 = BALL ? 40.0f : 0.0f;
            if (!BALL) {
                const float* bb = pbbox + (size_t)b * 4 * H * W;
                constexpr float sx = (float)W * ds, sy = (float)H * ds;
                t0 = bb[id]             * sx;
                t1 = bb[id + H * W]     * sy;
                t2 = bb[id + 2 * H * W] * sx;
                t3 = bb[id + 3 * H * W] * sy;
            }
            float bx = xc + t0, by = yc + t1;
            o0 = bx - 0.5f * t2;
            o1 = by - 0.5f * t3;
            o2 = bx + 0.5f * t2;
            o3 = by + 0.5f * t3;
        }
        float* op = outp + (size_t)threadIdx.x * 5;
        op[0] = o0; op[1] = o1; op[2] = o2; op[3] = o3; op[4] = val;
    }
}

__global__ __launch_bounds__(TPB) void stage2(const float* __restrict__ bmap,
                                              const float* __restrict__ pmap,
                                              const float* __restrict__ pbbox,
                                              const uint32_t* __restrict__ bkey,
                                              const uint32_t* __restrict__ pkey,
                                              float* __restrict__ out)
{
    extern __shared__ unsigned char smem[];
    if (blockIdx.x < NB) {
        int b = blockIdx.x;
        stage2_impl<HB, WB, NSB, true>(bmap, nullptr, bkey,
            out + (size_t)NB * KTOP * 5 + (size_t)b * KTOP * 5, b, smem);
    } else {
        int b = blockIdx.x - NB;
        stage2_impl<HP, WP, NSP, false>(pmap, pbbox, pkey,
            out + (size_t)b * KTOP * 5, b, smem);
    }
}

// ---- launch -----------------------------------------------------------------
extern "C" void kernel_launch(void* const* d_in, const int* in_sizes, int n_in,
                              void* d_out, int out_size, void* d_ws, size_t ws_size,
                              hipStream_t stream) {
    const float* pmap  = (const float*)d_in[0];   // [64,2,68,120]
    const float* pbbox = (const float*)d_in[1];   // [64,4,68,120]
    const float* bmap  = (const float*)d_in[2];   // [64,2,272,480]
    float* out = (float*)d_out;                   // player [64,100,5] then ball

    uint32_t* ws_bkey = (uint32_t*)d_ws;                       // 64*34*192 u32
    uint32_t* ws_pkey = ws_bkey + (size_t)NB * NSB * KSLOT;    // 64*9*192 u32
    // total ws: 2,113,536 B (within proven budget)

    // LDS: tile 19200 + surv 3072 + hist 1024 + outb 768 = 24064 B -> 4 blk/CU
    size_t lds1 = (size_t)(SR + 2) * WB * 4 + (size_t)CAP * 4 + 1024 + (size_t)KSLOT * 4;
    stage1<<<dim3(NSB + NSP, NB), TPB, lds1, stream>>>(bmap, pmap, ws_bkey, ws_pkey);

    // LDS: keys 26112 + hist 1024 + outb 2048 = 29184 B
    size_t lds2 = (size_t)NSB * KSLOT * 4 + 1024 + 2048;
    stage2<<<2 * NB, TPB, lds2, stream>>>(bmap, pmap, pbbox, ws_bkey, ws_pkey, out);
}